// Round 1
// baseline (634.816 us; speedup 1.0000x reference)
//
#include <hip/hip_runtime.h>

#define B_   4
#define CIN  64
#define COUT 64
#define H_   128
#define W_   128
#define NOFF 18      // 2*N offset channels
#define HW   (H_ * W_)

// ---------------------------------------------------------------------------
// Kernel A: 3x3 offset conv, 2-way split over input channels.
// grid = 2 * B_ * H_, block = 128 (lane = w). Each thread keeps 18 accs in
// registers so every x tap feeds 18 FMAs. Partial s=0 includes bias, s=1 not.
// off layout: off[s][b][k][h][w], s stride = B_*NOFF*HW.
// ---------------------------------------------------------------------------
__global__ __launch_bounds__(128) void k_offset_conv(
    const float* __restrict__ x, const float* __restrict__ w_off,
    const float* __restrict__ b_off, float* __restrict__ off)
{
    const int bix = blockIdx.x;
    const int s   = bix / (B_ * H_);          // 0 or 1: c-half
    const int rem = bix - s * (B_ * H_);
    const int b   = rem >> 7;
    const int h   = rem & 127;
    const int w   = threadIdx.x;              // 0..127

    float acc[NOFF];
#pragma unroll
    for (int k = 0; k < NOFF; ++k) acc[k] = (s == 0) ? b_off[k] : 0.f;

    const float* xb = x + (size_t)b * (CIN * HW);
    const int c0 = s * (CIN / 2);
    for (int c = c0; c < c0 + CIN / 2; ++c) {
        const float* xc = xb + c * HW;
#pragma unroll
        for (int kh = 0; kh < 3; ++kh) {
            const int r = h + kh - 1;
            float t0 = 0.f, t1 = 0.f, t2 = 0.f;
            if ((unsigned)r < (unsigned)H_) {
                const float* xr = xc + r * W_;
                t1 = xr[w];
                t0 = (w > 0) ? xr[w - 1] : 0.f;
                t2 = (w < W_ - 1) ? xr[w + 1] : 0.f;
            }
#pragma unroll
            for (int k = 0; k < NOFF; ++k) {
                const float* wr = w_off + ((k * CIN + c) * 3 + kh) * 3;
                acc[k] = fmaf(t0, wr[0], acc[k]);
                acc[k] = fmaf(t1, wr[1], acc[k]);
                acc[k] = fmaf(t2, wr[2], acc[k]);
            }
        }
    }

    float* ob = off + (size_t)s * (B_ * NOFF * HW)
                    + ((size_t)b * NOFF) * HW + h * W_ + w;
#pragma unroll
    for (int k = 0; k < NOFF; ++k) ob[(size_t)k * HW] = acc[k];
}

// ---------------------------------------------------------------------------
// Kernel W: transpose w_def [o][c][n] -> wT [c][o][n] (contiguous per c).
// ---------------------------------------------------------------------------
__global__ __launch_bounds__(256) void k_wt(
    const float* __restrict__ w_def, float* __restrict__ wT)
{
    const int i = blockIdx.x * 256 + threadIdx.x;
    if (i >= COUT * CIN * 9) return;
    const int o = i / (CIN * 9);
    const int r = i - o * (CIN * 9);
    const int c = r / 9;
    const int n = r - c * 9;
    wT[(c * COUT + o) * 9 + n] = w_def[i];
}

// ---------------------------------------------------------------------------
// Kernel B: bilinear gather + einsum.
// One wave per (b, h, w-tile of 64, o-half of 32); lane = w.
// Per-pixel sampling geometry precomputed once (indices clamped, pad handled
// by zeroing the bilinear weight -> branchless inner loop).
// grid = B_*H_*2*2/4 blocks of 256 threads (4 independent waves per block).
// ---------------------------------------------------------------------------
__global__ __launch_bounds__(256) void k_main(
    const float* __restrict__ x, const float* __restrict__ off,
    const float* __restrict__ wT, const float* __restrict__ b_def,
    float* __restrict__ out)
{
    const int lane  = threadIdx.x & 63;
    const int gw    = blockIdx.x * 4 + (threadIdx.x >> 6);
    const int ohalf = gw & 1;
    const int wt    = (gw >> 1) & 1;
    const int h     = (gw >> 2) & 127;
    const int b     = gw >> 9;
    const int w     = wt * 64 + lane;

    int   i_lt[9], i_rb[9], i_lb[9], i_rt[9];
    float g_lt[9], g_rb[9], g_lb[9], g_rt[9];

    const float* offp = off + ((size_t)b * NOFF) * HW + h * W_ + w;
    const size_t SOFF = (size_t)B_ * NOFF * HW;   // second partial
#pragma unroll
    for (int n = 0; n < 9; ++n) {
        const float ox = offp[(size_t)n * HW] + offp[SOFF + (size_t)n * HW];
        const float oy = offp[(size_t)(9 + n) * HW] + offp[SOFF + (size_t)(9 + n) * HW];
        // px = (h+1) + pn_x + ox ; pn_x = n/3 - 1 ; exact small-int adds
        const float px = (float)(h + (n / 3)) + ox;
        const float py = (float)(w + (n % 3)) + oy;
        const float flx = floorf(px), fly = floorf(py);
        const float qlx = fminf(fmaxf(flx, 0.f), 129.f);
        const float qly = fminf(fmaxf(fly, 0.f), 129.f);
        const float qrx = fminf(fmaxf(flx + 1.f, 0.f), 129.f);
        const float qry = fminf(fmaxf(fly + 1.f, 0.f), 129.f);
        const float pxc = fminf(fmaxf(px, 0.f), 129.f);
        const float pyc = fminf(fmaxf(py, 0.f), 129.f);
        const float gxl = 1.f + (qlx - pxc);
        const float gxr = 1.f - (qrx - pxc);
        const float gyl = 1.f + (qly - pyc);
        const float gyr = 1.f - (qry - pyc);
        const int xl = (int)qlx, yl = (int)qly, xr = (int)qrx, yr = (int)qry;
        const int vxl = (xl >= 1) & (xl <= 128), vxr = (xr >= 1) & (xr <= 128);
        const int vyl = (yl >= 1) & (yl <= 128), vyr = (yr >= 1) & (yr <= 128);
        // pad corner => weight 0, index clamped to a safe in-bounds slot
        g_lt[n] = (vxl & vyl) ? gxl * gyl : 0.f;
        g_rb[n] = (vxr & vyr) ? gxr * gyr : 0.f;
        g_lb[n] = (vxl & vyr) ? gxl * gyr : 0.f;
        g_rt[n] = (vxr & vyl) ? gxr * gyl : 0.f;
        i_lt[n] = (vxl & vyl) ? (xl - 1) * W_ + (yl - 1) : 0;
        i_rb[n] = (vxr & vyr) ? (xr - 1) * W_ + (yr - 1) : 0;
        i_lb[n] = (vxl & vyr) ? (xl - 1) * W_ + (yr - 1) : 0;
        i_rt[n] = (vxr & vyl) ? (xr - 1) * W_ + (yl - 1) : 0;
    }

    float acc[32];
#pragma unroll
    for (int o = 0; o < 32; ++o) acc[o] = 0.f;

    const float* xb = x + (size_t)b * (CIN * HW);
    for (int c = 0; c < CIN; ++c) {
        const float* xc = xb + c * HW;
        float xo[9];
#pragma unroll
        for (int n = 0; n < 9; ++n) {
            const float vlt = xc[i_lt[n]];
            const float vrb = xc[i_rb[n]];
            const float vlb = xc[i_lb[n]];
            const float vrt = xc[i_rt[n]];
            xo[n] = fmaf(g_lt[n], vlt,
                    fmaf(g_rb[n], vrb,
                    fmaf(g_lb[n], vlb, g_rt[n] * vrt)));
        }
        const float* wp = wT + ((size_t)c * COUT + ohalf * 32) * 9;
#pragma unroll
        for (int o = 0; o < 32; ++o) {
            float a = acc[o];
#pragma unroll
            for (int n = 0; n < 9; ++n) a = fmaf(wp[o * 9 + n], xo[n], a);
            acc[o] = a;
        }
    }

    const int obase = ohalf * 32;
    float* op = out + (((size_t)b * COUT + obase) * H_ + h) * W_ + w;
#pragma unroll
    for (int o = 0; o < 32; ++o)
        op[(size_t)o * HW] = acc[o] + b_def[obase + o];
}

// ---------------------------------------------------------------------------
extern "C" void kernel_launch(void* const* d_in, const int* in_sizes, int n_in,
                              void* d_out, int out_size, void* d_ws, size_t ws_size,
                              hipStream_t stream)
{
    const float* x     = (const float*)d_in[0];
    const float* w_off = (const float*)d_in[1];
    const float* b_off = (const float*)d_in[2];
    const float* w_def = (const float*)d_in[3];
    const float* b_def = (const float*)d_in[4];
    float* out = (float*)d_out;

    float* off = (float*)d_ws;                              // 2 * B*18*H*W floats
    float* wT  = off + 2 * (size_t)B_ * NOFF * HW;          // 64*64*9 floats

    k_offset_conv<<<2 * B_ * H_, 128, 0, stream>>>(x, w_off, b_off, off);
    k_wt<<<(COUT * CIN * 9 + 255) / 256, 256, 0, stream>>>(w_def, wT);
    k_main<<<(B_ * H_ * 2 * 2) / 4, 256, 0, stream>>>(x, off, wT, b_def, out);
}

// Round 3
// 255.875 us; speedup vs baseline: 2.4810x; 2.4810x over previous
//
#include <hip/hip_runtime.h>

#define B_   4
#define CIN  64
#define COUT 64
#define H_   128
#define W_   128
#define NOFF 18      // 2*N offset channels
#define HW   (H_ * W_)
#define CS   4       // c-chunks per block in k_main
#define CC   (CIN / CS)

// ---------------------------------------------------------------------------
// Kernel W: weight re-layouts.
//  wT2[n][c][o] = w_def[o][c][n]   (einsum weights, 32 contiguous o per step)
//  wo2[c][t][k] = w_off[k][c][t]   (offset-conv weights, 54 contiguous per row)
// ---------------------------------------------------------------------------
__global__ __launch_bounds__(256) void k_wt(
    const float* __restrict__ w_def, const float* __restrict__ w_off,
    float* __restrict__ wT2, float* __restrict__ wo2)
{
    const int i = blockIdx.x * 256 + threadIdx.x;
    if (i < COUT * CIN * 9) {
        const int o = i / (CIN * 9);
        const int r = i - o * (CIN * 9);
        const int c = r / 9;
        const int n = r - c * 9;
        wT2[(n * CIN + c) * COUT + o] = w_def[i];
    }
    const int j = i - COUT * CIN * 9;
    if (j >= 0 && j < NOFF * CIN * 9) {
        const int k = j / (CIN * 9);
        const int r = j - k * (CIN * 9);
        const int c = r / 9;
        const int t = r - c * 9;          // kh*3+kw
        wo2[(c * 9 + t) * NOFF + k] = w_off[j];
    }
}

// ---------------------------------------------------------------------------
// Kernel A: 3x3 offset conv. grid = B*H blocks of 512 threads = 8 waves:
// (cq in 0..3) x (whalf in 0..1). Each wave: 16 channels, 18 accumulators.
// Cross-cq reduction via LDS; single full `off` buffer written (bias fused).
// ---------------------------------------------------------------------------
__global__ __launch_bounds__(512) void k_offset_conv(
    const float* __restrict__ x, const float* __restrict__ wo2,
    const float* __restrict__ b_off, float* __restrict__ off)
{
    const int tid   = threadIdx.x;
    const int lane  = tid & 63;
    const int whalf = (tid >> 6) & 1;
    const int cq    = tid >> 7;
    const int b     = blockIdx.x >> 7;
    const int h     = blockIdx.x & 127;
    const int w     = whalf * 64 + lane;

    float acc[NOFF];
#pragma unroll
    for (int k = 0; k < NOFF; ++k) acc[k] = 0.f;

    const int c0 = __builtin_amdgcn_readfirstlane(cq * (CIN / 4));
    const float* xb = x + (size_t)b * (CIN * HW) + (size_t)c0 * HW;

#pragma unroll 1
    for (int c = 0; c < CIN / 4; ++c) {
        const float* xc = xb + c * HW;
#pragma unroll
        for (int kh = 0; kh < 3; ++kh) {
            const int r = h + kh - 1;
            float t0 = 0.f, t1 = 0.f, t2 = 0.f;
            if ((unsigned)r < (unsigned)H_) {
                const float* xr = xc + r * W_;
                t1 = xr[w];
                t0 = (w > 0) ? xr[w - 1] : 0.f;
                t2 = (w < W_ - 1) ? xr[w + 1] : 0.f;
            }
            const float* wp = wo2 + ((c0 + c) * 9 + kh * 3) * NOFF;
#pragma unroll
            for (int k = 0; k < NOFF; ++k) acc[k] = fmaf(t0, wp[k], acc[k]);
#pragma unroll
            for (int k = 0; k < NOFF; ++k) acc[k] = fmaf(t1, wp[NOFF + k], acc[k]);
#pragma unroll
            for (int k = 0; k < NOFF; ++k) acc[k] = fmaf(t2, wp[2 * NOFF + k], acc[k]);
        }
    }

    __shared__ float red[2][NOFF][128];
    if (cq >= 2) {
#pragma unroll
        for (int k = 0; k < NOFF; ++k) red[cq - 2][k][w] = acc[k];
    }
    __syncthreads();
    if (cq < 2) {
#pragma unroll
        for (int k = 0; k < NOFF; ++k) acc[k] += red[cq][k][w];
    }
    __syncthreads();
    if (cq == 1) {
#pragma unroll
        for (int k = 0; k < NOFF; ++k) red[0][k][w] = acc[k];
    }
    __syncthreads();
    if (cq == 0) {
        float* ob = off + ((size_t)b * NOFF) * HW + h * W_ + w;
#pragma unroll
        for (int k = 0; k < NOFF; ++k)
            ob[(size_t)k * HW] = acc[k] + red[0][k][w] + b_off[k];   // FIX: add cq1+cq3 partial
    }
}

// ---------------------------------------------------------------------------
// Kernel B: bilinear gather + einsum.
// grid = B*H*2*2 blocks of 256 = 4 waves, one per 16-channel chunk of the
// same (b, h, w-tile, o-half). n-outer loop (geometry recomputed per tap,
// next-tap offsets prefetched), c-inner with scalar-broadcast weights.
// Cross-chunk reduction via LDS, single coalesced store.
// ---------------------------------------------------------------------------
__global__ __launch_bounds__(256) void k_main(
    const float* __restrict__ x, const float* __restrict__ off,
    const float* __restrict__ wT2, const float* __restrict__ b_def,
    float* __restrict__ out)
{
    const int tid   = threadIdx.x;
    const int lane  = tid & 63;
    const int cq    = tid >> 6;
    const int gw    = blockIdx.x;
    const int ohalf = gw & 1;
    const int wt    = (gw >> 1) & 1;
    const int h     = (gw >> 2) & 127;
    const int b     = gw >> 9;
    const int w     = wt * 64 + lane;
    const int obase = ohalf * 32;

    float acc[32];
#pragma unroll
    for (int o = 0; o < 32; ++o) acc[o] = 0.f;

    const int c0 = __builtin_amdgcn_readfirstlane(cq * CC);
    const float* xb   = x + (size_t)b * (CIN * HW) + (size_t)c0 * HW;
    const float* offp = off + ((size_t)b * NOFF) * HW + h * W_ + w;

    float oxN = offp[0];
    float oyN = offp[(size_t)9 * HW];

#pragma unroll 1
    for (int n = 0; n < 9; ++n) {
        const float ox = oxN, oy = oyN;
        if (n < 8) {
            oxN = offp[(size_t)(n + 1) * HW];
            oyN = offp[(size_t)(n + 10) * HW];
        }
        const float px = (float)(h + n / 3) + ox;
        const float py = (float)(w + n % 3) + oy;
        const float flx = floorf(px), fly = floorf(py);
        const float qlx = fminf(fmaxf(flx, 0.f), 129.f);
        const float qly = fminf(fmaxf(fly, 0.f), 129.f);
        const float qrx = fminf(fmaxf(flx + 1.f, 0.f), 129.f);
        const float qry = fminf(fmaxf(fly + 1.f, 0.f), 129.f);
        const float pxc = fminf(fmaxf(px, 0.f), 129.f);
        const float pyc = fminf(fmaxf(py, 0.f), 129.f);
        const float gxl = 1.f + (qlx - pxc);
        const float gxr = 1.f - (qrx - pxc);
        const float gyl = 1.f + (qly - pyc);
        const float gyr = 1.f - (qry - pyc);
        const int xl = (int)qlx, yl = (int)qly, xr = (int)qrx, yr = (int)qry;
        const int vxl = (xl >= 1) & (xl <= 128), vxr = (xr >= 1) & (xr <= 128);
        const int vyl = (yl >= 1) & (yl <= 128), vyr = (yr >= 1) & (yr <= 128);
        const float glt = (vxl & vyl) ? gxl * gyl : 0.f;
        const float grb = (vxr & vyr) ? gxr * gyr : 0.f;
        const float glb = (vxl & vyr) ? gxl * gyr : 0.f;
        const float grt = (vxr & vyl) ? gxr * gyl : 0.f;
        const int ilt = (vxl & vyl) ? (xl - 1) * W_ + (yl - 1) : 0;
        const int irb = (vxr & vyr) ? (xr - 1) * W_ + (yr - 1) : 0;
        const int ilb = (vxl & vyr) ? (xl - 1) * W_ + (yr - 1) : 0;
        const int irt = (vxr & vyl) ? (xr - 1) * W_ + (yl - 1) : 0;

        const int wb = __builtin_amdgcn_readfirstlane((n * CIN + c0) * COUT + obase);
        const float* wp = wT2 + wb;

#pragma unroll 4
        for (int c = 0; c < CC; ++c) {
            const float* xc = xb + c * HW;
            const float xo = fmaf(glt, xc[ilt],
                             fmaf(grb, xc[irb],
                             fmaf(glb, xc[ilb], grt * xc[irt])));
            const float* wc = wp + c * COUT;
#pragma unroll
            for (int o = 0; o < 32; ++o) acc[o] = fmaf(wc[o], xo, acc[o]);
        }
    }

    __shared__ float red[2][32][64];
    if (cq >= 2) {
#pragma unroll
        for (int o = 0; o < 32; ++o) red[cq - 2][o][lane] = acc[o];
    }
    __syncthreads();
    if (cq < 2) {
#pragma unroll
        for (int o = 0; o < 32; ++o) acc[o] += red[cq][o][lane];
    }
    __syncthreads();
    if (cq == 1) {
#pragma unroll
        for (int o = 0; o < 32; ++o) red[0][o][lane] = acc[o];
    }
    __syncthreads();
    if (cq == 0) {
        float* op = out + (((size_t)b * COUT + obase) * H_ + h) * W_ + w;
#pragma unroll
        for (int o = 0; o < 32; ++o)
            op[(size_t)o * HW] = acc[o] + red[0][o][lane] + b_def[obase + o];  // FIX: add cq1+cq3 partial
    }
}

// ---------------------------------------------------------------------------
extern "C" void kernel_launch(void* const* d_in, const int* in_sizes, int n_in,
                              void* d_out, int out_size, void* d_ws, size_t ws_size,
                              hipStream_t stream)
{
    const float* x     = (const float*)d_in[0];
    const float* w_off = (const float*)d_in[1];
    const float* b_off = (const float*)d_in[2];
    const float* w_def = (const float*)d_in[3];
    const float* b_def = (const float*)d_in[4];
    float* out = (float*)d_out;

    float* off = (float*)d_ws;                       // B*18*HW floats (4.72 MB)
    float* wT2 = off + (size_t)B_ * NOFF * HW;       // 9*64*64
    float* wo2 = wT2 + 9 * CIN * COUT;               // 64*9*18

    k_wt<<<(COUT * CIN * 9 + NOFF * CIN * 9 + 255) / 256, 256, 0, stream>>>(
        w_def, w_off, wT2, wo2);
    k_offset_conv<<<B_ * H_, 512, 0, stream>>>(x, wo2, b_off, off);
    k_main<<<B_ * H_ * 2 * 2, 256, 0, stream>>>(x, off, wT2, b_def, out);
}

// Round 4
// 111.867 us; speedup vs baseline: 5.6747x; 2.2873x over previous
//
#include <hip/hip_runtime.h>

#define B_   4
#define CIN  64
#define COUT 64
#define H_   128
#define W_   128
#define NOFF 18      // 2*N offset channels
#define HW   (H_ * W_)
#define HP   130
#define WP   130

typedef __attribute__((ext_vector_type(8))) short bf16x8;
typedef __attribute__((ext_vector_type(4))) float f32x4;

__device__ __forceinline__ unsigned short f2bf(float f) {
    unsigned int u = __float_as_uint(f);
    return (unsigned short)((u + 0x7fffu + ((u >> 16) & 1u)) >> 16);
}

// ===========================================================================
// NEW PATH
// ===========================================================================

// wB[kblk][nblk][lane][j] = bf16(w_def[o][c][n]), o = nblk*16+(lane&15),
// K = kblk*32 + 8*(lane>>4) + j, n = K>>6, c = K&63.   (MFMA B-frag order)
// wo2[c][t][k] = w_off[k][c][t]  (offset-conv weights, fp32)
__global__ __launch_bounds__(256) void k_wt_new(
    const float* __restrict__ w_def, const float* __restrict__ w_off,
    unsigned short* __restrict__ wB, float* __restrict__ wo2)
{
    const int i = blockIdx.x * 256 + threadIdx.x;
    if (i < 18 * 4 * 64) {
        const int kblk = i >> 8;
        const int nblk = (i >> 6) & 3;
        const int lane = i & 63;
        const int o = nblk * 16 + (lane & 15);
        unsigned int pk[4];
#pragma unroll
        for (int d = 0; d < 4; ++d) {
            unsigned int v = 0;
#pragma unroll
            for (int e = 0; e < 2; ++e) {
                const int j = d * 2 + e;
                const int K = kblk * 32 + 8 * (lane >> 4) + j;
                const int n = K >> 6, c = K & 63;
                v |= (unsigned int)f2bf(w_def[((size_t)o * 64 + c) * 9 + n]) << (16 * e);
            }
            pk[d] = v;
        }
        *(uint4*)(wB + (size_t)i * 8) = make_uint4(pk[0], pk[1], pk[2], pk[3]);
    }
    if (i < NOFF * CIN * 9) {
        const int k = i / (CIN * 9);
        const int r = i - k * (CIN * 9);
        const int c = r / 9;
        const int t = r - c * 9;
        wo2[(c * 9 + t) * NOFF + k] = w_off[i];
    }
}

// xt[b][hp][wp][c] (f32, padded frame 130x130, zeros on border)
__global__ __launch_bounds__(256) void k_xt(
    const float* __restrict__ x, float* __restrict__ xt)
{
    const int b  = blockIdx.x / HP;
    const int hp = blockIdx.x - b * HP;
    const int c  = threadIdx.x & 63;
    const int wq = threadIdx.x >> 6;
    float* dst = xt + (((size_t)b * HP + hp) * WP) * 64 + c;
    for (int wp = wq; wp < WP; wp += 4) {
        float v = 0.f;
        if (hp >= 1 && hp <= H_ && wp >= 1 && wp <= W_)
            v = x[(((size_t)b * CIN + c) * H_ + (hp - 1)) * W_ + (wp - 1)];
        dst[(size_t)wp * 64] = v;
    }
}

// 3x3 offset conv (unchanged from round 3). grid = B*H blocks of 512.
__global__ __launch_bounds__(512) void k_offset_conv(
    const float* __restrict__ x, const float* __restrict__ wo2,
    const float* __restrict__ b_off, float* __restrict__ off)
{
    const int tid   = threadIdx.x;
    const int lane  = tid & 63;
    const int whalf = (tid >> 6) & 1;
    const int cq    = tid >> 7;
    const int b     = blockIdx.x >> 7;
    const int h     = blockIdx.x & 127;
    const int w     = whalf * 64 + lane;

    float acc[NOFF];
#pragma unroll
    for (int k = 0; k < NOFF; ++k) acc[k] = 0.f;

    const int c0 = __builtin_amdgcn_readfirstlane(cq * (CIN / 4));
    const float* xb = x + (size_t)b * (CIN * HW) + (size_t)c0 * HW;

#pragma unroll 1
    for (int c = 0; c < CIN / 4; ++c) {
        const float* xc = xb + c * HW;
#pragma unroll
        for (int kh = 0; kh < 3; ++kh) {
            const int r = h + kh - 1;
            float t0 = 0.f, t1 = 0.f, t2 = 0.f;
            if ((unsigned)r < (unsigned)H_) {
                const float* xr = xc + r * W_;
                t1 = xr[w];
                t0 = (w > 0) ? xr[w - 1] : 0.f;
                t2 = (w < W_ - 1) ? xr[w + 1] : 0.f;
            }
            const float* wp = wo2 + ((c0 + c) * 9 + kh * 3) * NOFF;
#pragma unroll
            for (int k = 0; k < NOFF; ++k) acc[k] = fmaf(t0, wp[k], acc[k]);
#pragma unroll
            for (int k = 0; k < NOFF; ++k) acc[k] = fmaf(t1, wp[NOFF + k], acc[k]);
#pragma unroll
            for (int k = 0; k < NOFF; ++k) acc[k] = fmaf(t2, wp[2 * NOFF + k], acc[k]);
        }
    }

    __shared__ float red[2][NOFF][128];
    if (cq >= 2) {
#pragma unroll
        for (int k = 0; k < NOFF; ++k) red[cq - 2][k][w] = acc[k];
    }
    __syncthreads();
    if (cq < 2) {
#pragma unroll
        for (int k = 0; k < NOFF; ++k) acc[k] += red[cq][k][w];
    }
    __syncthreads();
    if (cq == 1) {
#pragma unroll
        for (int k = 0; k < NOFF; ++k) red[0][k][w] = acc[k];
    }
    __syncthreads();
    if (cq == 0) {
        float* ob = off + ((size_t)b * NOFF) * HW + h * W_ + w;
#pragma unroll
        for (int k = 0; k < NOFF; ++k)
            ob[(size_t)k * HW] = acc[k] + red[0][k][w] + b_off[k];
    }
}

// Gather + bilinear -> xoff[px][n*64+c] bf16.  grid = 1024, block 256.
// Phase 1: lane = pixel, geometry for taps n = wv, wv+4, wv+8 -> LDS.
// Phase 2: lane = channel, 4 coalesced corner loads + 3 FMA per (px,n).
__global__ __launch_bounds__(256) void k_gather(
    const float* __restrict__ xt, const float* __restrict__ off,
    unsigned short* __restrict__ xoff)
{
    const int tid   = threadIdx.x;
    const int lane  = tid & 63;
    const int wv    = tid >> 6;
    const int pxblk = blockIdx.x;
    const int b     = pxblk >> 8;
    const int h     = (pxblk >> 1) & 127;
    const int w0    = (pxblk & 1) * 64;

    __shared__ uint2  geoI[9][64];
    __shared__ float4 geoG[9][64];

    // ---- phase 1: geometry (lane = pixel) ----
    {
        const int wpix = w0 + lane;
        const float* offp = off + ((size_t)b * NOFF) * HW + h * W_ + wpix;
        for (int n = wv; n < 9; n += 4) {
            const float ox = offp[(size_t)n * HW];
            const float oy = offp[(size_t)(n + 9) * HW];
            const float px = (float)(h + n / 3) + ox;
            const float py = (float)(wpix + n % 3) + oy;
            const float flx = floorf(px), fly = floorf(py);
            const float qlx = fminf(fmaxf(flx, 0.f), 129.f);
            const float qly = fminf(fmaxf(fly, 0.f), 129.f);
            const float qrx = fminf(fmaxf(flx + 1.f, 0.f), 129.f);
            const float qry = fminf(fmaxf(fly + 1.f, 0.f), 129.f);
            const float pxc = fminf(fmaxf(px, 0.f), 129.f);
            const float pyc = fminf(fmaxf(py, 0.f), 129.f);
            const float gxl = 1.f + (qlx - pxc);
            const float gxr = 1.f - (qrx - pxc);
            const float gyl = 1.f + (qly - pyc);
            const float gyr = 1.f - (qry - pyc);
            const int xl = (int)qlx, yl = (int)qly, xr = (int)qrx, yr = (int)qry;
            const unsigned int ilt = (unsigned)(xl * WP + yl);
            const unsigned int irb = (unsigned)(xr * WP + yr);
            const unsigned int ilb = (unsigned)(xl * WP + yr);
            const unsigned int irt = (unsigned)(xr * WP + yl);
            geoI[n][lane] = make_uint2(ilt | (irb << 16), ilb | (irt << 16));
            geoG[n][lane] = make_float4(gxl * gyl, gxr * gyr, gxl * gyr, gxr * gyl);
        }
    }
    __syncthreads();

    // ---- phase 2: gather (lane = channel) ----
    const float* xtb = xt + (size_t)b * (HP * WP * 64);
    unsigned short* xo = xoff + (size_t)(pxblk * 64) * 576;

#pragma unroll 1
    for (int pxi = 0; pxi < 16; ++pxi) {
        const int pxl = wv * 16 + pxi;
#pragma unroll 3
        for (int n = 0; n < 9; ++n) {
            const uint2  gi = geoI[n][pxl];
            const float4 gg = geoG[n][pxl];
            const float vlt = xtb[(size_t)(gi.x & 0xffffu) * 64 + lane];
            const float vrb = xtb[(size_t)(gi.x >> 16)     * 64 + lane];
            const float vlb = xtb[(size_t)(gi.y & 0xffffu) * 64 + lane];
            const float vrt = xtb[(size_t)(gi.y >> 16)     * 64 + lane];
            const float v = fmaf(gg.x, vlt, fmaf(gg.y, vrb,
                            fmaf(gg.z, vlb, gg.w * vrt)));
            xo[(size_t)pxl * 576 + n * 64 + lane] = f2bf(v);
        }
    }
}

// GEMM: out[px][o] = xoff[px][K] * W[K][o], K = 576, via 16x16x32 bf16 MFMA.
// grid = 1024 blocks of 256 (4 waves, each 16 px rows x 64 o).
__global__ __launch_bounds__(256) void k_gemm(
    const unsigned short* __restrict__ xoff, const unsigned short* __restrict__ wB,
    const float* __restrict__ b_def, float* __restrict__ out)
{
    const int tid  = threadIdx.x;
    const int lane = tid & 63;
    const int wv   = tid >> 6;
    const int pxblk = blockIdx.x;
    const int row  = lane & 15;
    const int g    = lane >> 4;

    const unsigned short* Ap = xoff + (size_t)(pxblk * 64 + wv * 16 + row) * 576 + g * 8;
    const unsigned short* Bp = wB + (size_t)lane * 8;

    f32x4 acc0 = {0.f, 0.f, 0.f, 0.f};
    f32x4 acc1 = {0.f, 0.f, 0.f, 0.f};
    f32x4 acc2 = {0.f, 0.f, 0.f, 0.f};
    f32x4 acc3 = {0.f, 0.f, 0.f, 0.f};

#pragma unroll 3
    for (int kb = 0; kb < 18; ++kb) {
        const bf16x8 a  = *(const bf16x8*)(Ap + kb * 32);
        const bf16x8 b0 = *(const bf16x8*)(Bp + (size_t)(kb * 4 + 0) * 512);
        const bf16x8 b1 = *(const bf16x8*)(Bp + (size_t)(kb * 4 + 1) * 512);
        const bf16x8 b2 = *(const bf16x8*)(Bp + (size_t)(kb * 4 + 2) * 512);
        const bf16x8 b3 = *(const bf16x8*)(Bp + (size_t)(kb * 4 + 3) * 512);
        acc0 = __builtin_amdgcn_mfma_f32_16x16x32_bf16(a, b0, acc0, 0, 0, 0);
        acc1 = __builtin_amdgcn_mfma_f32_16x16x32_bf16(a, b1, acc1, 0, 0, 0);
        acc2 = __builtin_amdgcn_mfma_f32_16x16x32_bf16(a, b2, acc2, 0, 0, 0);
        acc3 = __builtin_amdgcn_mfma_f32_16x16x32_bf16(a, b3, acc3, 0, 0, 0);
    }

    const int p_base = pxblk * 64 + wv * 16 + 4 * g;
#pragma unroll
    for (int i = 0; i < 4; ++i) {
        const int o = i * 16 + row;
        const float bias = b_def[o];
        const f32x4 A = (i == 0) ? acc0 : (i == 1) ? acc1 : (i == 2) ? acc2 : acc3;
#pragma unroll
        for (int r = 0; r < 4; ++r) {
            const int p  = p_base + r;
            const int b  = p >> 14;
            const int hw = p & 16383;
            out[((size_t)(b * COUT + o)) * HW + hw] = A[r] + bias;
        }
    }
}

// ===========================================================================
// FALLBACK PATH (round-3, used only if ws is too small)
// ===========================================================================
__global__ __launch_bounds__(256) void k_wt_old(
    const float* __restrict__ w_def, const float* __restrict__ w_off,
    float* __restrict__ wT2, float* __restrict__ wo2)
{
    const int i = blockIdx.x * 256 + threadIdx.x;
    if (i < COUT * CIN * 9) {
        const int o = i / (CIN * 9);
        const int r = i - o * (CIN * 9);
        const int c = r / 9;
        const int n = r - c * 9;
        wT2[(n * CIN + c) * COUT + o] = w_def[i];
    }
    const int j = i - COUT * CIN * 9;
    if (j >= 0 && j < NOFF * CIN * 9) {
        const int k = j / (CIN * 9);
        const int r = j - k * (CIN * 9);
        const int c = r / 9;
        const int t = r - c * 9;
        wo2[(c * 9 + t) * NOFF + k] = w_off[j];
    }
}

__global__ __launch_bounds__(256) void k_main_old(
    const float* __restrict__ x, const float* __restrict__ off,
    const float* __restrict__ wT2, const float* __restrict__ b_def,
    float* __restrict__ out)
{
    const int tid   = threadIdx.x;
    const int lane  = tid & 63;
    const int cq    = tid >> 6;
    const int gw    = blockIdx.x;
    const int ohalf = gw & 1;
    const int wt    = (gw >> 1) & 1;
    const int h     = (gw >> 2) & 127;
    const int b     = gw >> 9;
    const int w     = wt * 64 + lane;
    const int obase = ohalf * 32;

    float acc[32];
#pragma unroll
    for (int o = 0; o < 32; ++o) acc[o] = 0.f;

    const int c0 = __builtin_amdgcn_readfirstlane(cq * 16);
    const float* xb   = x + (size_t)b * (CIN * HW) + (size_t)c0 * HW;
    const float* offp = off + ((size_t)b * NOFF) * HW + h * W_ + w;

    float oxN = offp[0];
    float oyN = offp[(size_t)9 * HW];

#pragma unroll 1
    for (int n = 0; n < 9; ++n) {
        const float ox = oxN, oy = oyN;
        if (n < 8) {
            oxN = offp[(size_t)(n + 1) * HW];
            oyN = offp[(size_t)(n + 10) * HW];
        }
        const float px = (float)(h + n / 3) + ox;
        const float py = (float)(w + n % 3) + oy;
        const float flx = floorf(px), fly = floorf(py);
        const float qlx = fminf(fmaxf(flx, 0.f), 129.f);
        const float qly = fminf(fmaxf(fly, 0.f), 129.f);
        const float qrx = fminf(fmaxf(flx + 1.f, 0.f), 129.f);
        const float qry = fminf(fmaxf(fly + 1.f, 0.f), 129.f);
        const float pxc = fminf(fmaxf(px, 0.f), 129.f);
        const float pyc = fminf(fmaxf(py, 0.f), 129.f);
        const float gxl = 1.f + (qlx - pxc);
        const float gxr = 1.f - (qrx - pxc);
        const float gyl = 1.f + (qly - pyc);
        const float gyr = 1.f - (qry - pyc);
        const int xl = (int)qlx, yl = (int)qly, xr = (int)qrx, yr = (int)qry;
        const int vxl = (xl >= 1) & (xl <= 128), vxr = (xr >= 1) & (xr <= 128);
        const int vyl = (yl >= 1) & (yl <= 128), vyr = (yr >= 1) & (yr <= 128);
        const float glt = (vxl & vyl) ? gxl * gyl : 0.f;
        const float grb = (vxr & vyr) ? gxr * gyr : 0.f;
        const float glb = (vxl & vyr) ? gxl * gyr : 0.f;
        const float grt = (vxr & vyl) ? gxr * gyl : 0.f;
        const int ilt = (vxl & vyl) ? (xl - 1) * W_ + (yl - 1) : 0;
        const int irb = (vxr & vyr) ? (xr - 1) * W_ + (yr - 1) : 0;
        const int ilb = (vxl & vyr) ? (xl - 1) * W_ + (yr - 1) : 0;
        const int irt = (vxr & vyl) ? (xr - 1) * W_ + (yl - 1) : 0;

        const int wb = __builtin_amdgcn_readfirstlane((n * CIN + c0) * COUT + obase);
        const float* wp = wT2 + wb;

#pragma unroll 4
        for (int c = 0; c < 16; ++c) {
            const float* xc = xb + c * HW;
            const float xo = fmaf(glt, xc[ilt],
                             fmaf(grb, xc[irb],
                             fmaf(glb, xc[ilb], grt * xc[irt])));
            const float* wc = wp + c * COUT;
#pragma unroll
            for (int o = 0; o < 32; ++o) acc[o] = fmaf(wc[o], xo, acc[o]);
        }
    }

    __shared__ float red[2][32][64];
    if (cq >= 2) {
#pragma unroll
        for (int o = 0; o < 32; ++o) red[cq - 2][o][lane] = acc[o];
    }
    __syncthreads();
    if (cq < 2) {
#pragma unroll
        for (int o = 0; o < 32; ++o) acc[o] += red[cq][o][lane];
    }
    __syncthreads();
    if (cq == 1) {
#pragma unroll
        for (int o = 0; o < 32; ++o) red[0][o][lane] = acc[o];
    }
    __syncthreads();
    if (cq == 0) {
        float* op = out + (((size_t)b * COUT + obase) * H_ + h) * W_ + w;
#pragma unroll
        for (int o = 0; o < 32; ++o)
            op[(size_t)o * HW] = acc[o] + red[0][o][lane] + b_def[obase + o];
    }
}

// ===========================================================================
extern "C" void kernel_launch(void* const* d_in, const int* in_sizes, int n_in,
                              void* d_out, int out_size, void* d_ws, size_t ws_size,
                              hipStream_t stream)
{
    const float* x     = (const float*)d_in[0];
    const float* w_off = (const float*)d_in[1];
    const float* b_off = (const float*)d_in[2];
    const float* w_def = (const float*)d_in[3];
    const float* b_def = (const float*)d_in[4];
    float* out = (float*)d_out;

    char* ws = (char*)d_ws;

    // byte offsets (new path)
    const size_t OFF_O  = 0;                     // off  : f32 [B][18][HW]   4,718,592 B
    const size_t WO2_O  = 4718592;               // wo2  : f32 10368          41,472 B
    const size_t WB_O   = 4760064;               // wB   : bf16 36864         73,728 B
    const size_t XT_O   = 4833792;               // xt   : f32 [B][130][130][64] 17,305,600 B
    const size_t XOFF_O = 22139392;              // xoff : bf16 65536x576  75,497,472 B
    const size_t NEED   = 97636864;

    if (ws_size >= NEED) {
        float*          off  = (float*)(ws + OFF_O);
        float*          wo2  = (float*)(ws + WO2_O);
        unsigned short* wB   = (unsigned short*)(ws + WB_O);
        float*          xt   = (float*)(ws + XT_O);
        unsigned short* xoff = (unsigned short*)(ws + XOFF_O);

        k_wt_new<<<(NOFF * CIN * 9 + 255) / 256, 256, 0, stream>>>(w_def, w_off, wB, wo2);
        k_xt<<<B_ * HP, 256, 0, stream>>>(x, xt);
        k_offset_conv<<<B_ * H_, 512, 0, stream>>>(x, wo2, b_off, off);
        k_gather<<<B_ * HW / 64, 256, 0, stream>>>(xt, off, xoff);
        k_gemm<<<B_ * HW / 64, 256, 0, stream>>>(xoff, wB, b_def, out);
    } else {
        float* off = (float*)d_ws;
        float* wT2 = off + (size_t)B_ * NOFF * HW;
        float* wo2 = wT2 + 9 * CIN * COUT;
        k_wt_old<<<(COUT * CIN * 9 + NOFF * CIN * 9 + 255) / 256, 256, 0, stream>>>(
            w_def, w_off, wT2, wo2);
        k_offset_conv<<<B_ * H_, 512, 0, stream>>>(x, wo2, b_off, off);
        k_main_old<<<B_ * H_ * 2 * 2, 256, 0, stream>>>(x, off, wT2, b_def, out);
    }
}